// Round 9
// baseline (300.977 us; speedup 1.0000x reference)
//
#include <hip/hip_runtime.h>

typedef __bf16 bf16x8 __attribute__((ext_vector_type(8)));
typedef float  f32x4  __attribute__((ext_vector_type(4)));
typedef float  f32x16 __attribute__((ext_vector_type(16)));
typedef unsigned short ushort8 __attribute__((ext_vector_type(8)));

#define KDIM  4096
#define NDIM  4096
#define REDIN 2048

static __device__ __forceinline__ unsigned short f2bf(float f) {
    return __builtin_bit_cast(unsigned short, (__bf16)f);
}

typedef __attribute__((address_space(3))) void       lds_void;
typedef const __attribute__((address_space(1))) void gbl_cvoid;

static __device__ __forceinline__ void gload16(const void* g, void* l) {
    __builtin_amdgcn_global_load_lds((gbl_cvoid*)g, (lds_void*)l, 16, 0, 0);
}

// ---------------- prep 1: x fp32 -> bf16 [M][K] ----------------
__global__ void cvt_x(const float* __restrict__ x, unsigned short* __restrict__ xb,
                      long n8) {
    long idx = (long)blockIdx.x * blockDim.x + threadIdx.x;
    long stride = (long)gridDim.x * blockDim.x;
    for (long i = idx; i < n8; i += stride) {
        const float4 a = ((const float4*)x)[2 * i];
        const float4 b = ((const float4*)x)[2 * i + 1];
        ushort8 s;
        s[0] = f2bf(a.x); s[1] = f2bf(a.y); s[2] = f2bf(a.z); s[3] = f2bf(a.w);
        s[4] = f2bf(b.x); s[5] = f2bf(b.y); s[6] = f2bf(b.z); s[7] = f2bf(b.w);
        ((ushort8*)xb)[i] = s;
    }
}

// ---------------- prep 2: weight -> rotation-expanded bf16 [N][K] ----------------
__global__ void expand_w(const float* __restrict__ w, unsigned short* __restrict__ wx,
                         const int* __restrict__ rn) {
    const int R0 = rn[0], R1 = rn[1], R2 = rn[2], R3 = rn[3];
    const long total = (long)NDIM * (KDIM / 8);
    long idx = (long)blockIdx.x * blockDim.x + threadIdx.x;
    long stride = (long)gridDim.x * blockDim.x;
    for (long t = idx; t < total; t += stride) {
        const int kp = (int)(t & (KDIM / 8 - 1));
        const int n  = (int)(t >> 9);
        const int k0 = kp * 8;
        const int i  = k0 >> 5;
        const int kk0 = k0 & 31;
        const int it = i >> 1;
        const int h  = R3 + R2 * (n >> 5) + R1 * (it + 1) + R0 * ((i & 1) + 1);
        const int off = 32 - ((h << 2) & 31);
        const float* src = w + (long)n * REDIN + it * 32;
        ushort8 s;
#pragma unroll
        for (int q = 0; q < 8; ++q)
            s[q] = f2bf(src[(kk0 + q + off) & 31]);
        ((ushort8*)wx)[t] = s;
    }
}

// ======== main GEMM: 256x256, BK=64, 2-buf ring, 4 phases/group (R7 schedule), 32x32x16 MFMA ========
// 8 waves 2Mx4N, per-wave 128x64 out = 4m x 2n tiles of 32x32. LDS as R7:
// A[2buf][2half(M)][128][64]bf16 (64KB) + B same (64KB). Bank swizzle: phys 16B slot =
// logical ^ (row&7); linear gload dest + inverse-swizzled global source + swizzled ds_read.
// Frag layout (32x32x16): A/B row = lane&31, k = (lane>>5)*8 + e (structural analogue of
// the verified 16x16x32 load; identical k-map on A and B cancels any k-permutation).
// C/D: col = lane&31, row = (reg&3) + 8*(reg>>2) + 4*(lane>>5)  [HW-verified m74/m101].
// Group u (tile u from buf u&1), 4 phases, ONE barrier per phase (R7-verified hazard graph):
//   P1: read A(mf0-1)x8 + B(nf0)x4; stage A(u+1)h0; lgkm(8); BAR; lgkm(0); 8 MFMA(m-lo,n0)
//   P2: read B(nf1)x4;              stage A(u+1)h1;          BAR; lgkm(0); 8 MFMA(m-lo,n1)
//   P3: read A(mf2-3)x8;            stage B(u+2)h0;          BAR; lgkm(0); 8 MFMA(m-hi,n1)
//   P4: stage B(u+2)h1; 8 MFMA(m-hi,n0); vmcnt(4); BAR

#define STAGE_H(MAT, T, HALF)                                               \
  {                                                                         \
    char* _d = (char*)lds##MAT + ((((T) & 1) * 2 + (HALF)) * 16384) + tid * 16; \
    const unsigned short* _s = src##MAT + (size_t)((HALF) * 128) * KDIM + (size_t)(T) * 64; \
    gload16(_s, _d);                                                        \
    gload16(_s + (size_t)64 * KDIM, _d + 8192);                             \
  }

// read A pair (mf = MP*2 + i), 4 k-steps each: 8 x ds_read_b128
#define READ_A32(PA, MP)                                                    \
  _Pragma("unroll")                                                         \
  for (int _i = 0; _i < 2; ++_i)                                            \
    _Pragma("unroll")                                                       \
    for (int _ks = 0; _ks < 4; ++_ks)                                       \
      a_[_i][_ks] = *(const bf16x8*)((PA) + (MP) * 8192 + _i * 4096 + (roff32 ^ (_ks << 5)));

// read B group NF (32 cols), 4 k-steps: 4 x ds_read_b128
#define READ_B32(PB, NF)                                                    \
  _Pragma("unroll")                                                         \
  for (int _ks = 0; _ks < 4; ++_ks)                                         \
    b_[NF][_ks] = *(const bf16x8*)((PB) + (NF) * 4096 + (roff32 ^ (_ks << 5)));

#define MFMA_P(MP, NF)                                                      \
  __builtin_amdgcn_s_setprio(1);                                            \
  _Pragma("unroll")                                                         \
  for (int _ks = 0; _ks < 4; ++_ks)                                         \
    _Pragma("unroll")                                                       \
    for (int _i = 0; _i < 2; ++_i)                                          \
      acc32[(MP) * 2 + _i][NF] = __builtin_amdgcn_mfma_f32_32x32x16_bf16(   \
          a_[_i][_ks], b_[NF][_ks], acc32[(MP) * 2 + _i][NF], 0, 0, 0);     \
  __builtin_amdgcn_s_setprio(0);

#define SB __builtin_amdgcn_sched_barrier(0)
#define BAR __builtin_amdgcn_s_barrier()

#define GROUP(U, BUF, STG, VMSTR)                                           \
  {                                                                         \
    const char* paA = ldsAc + ((BUF) * 2 + wr) * 16384;                     \
    const char* pbB = ldsBc + ((BUF) * 2 + bh) * 16384 + bhw;               \
    /* P1 */                                                                \
    READ_A32(paA, 0)                                                        \
    READ_B32(pbB, 0)                                                        \
    if ((STG) >= 1) STAGE_H(A, (U) + 1, 0);                                 \
    asm volatile("s_waitcnt lgkmcnt(8)" ::: "memory");                      \
    SB; BAR;                                                                \
    asm volatile("s_waitcnt lgkmcnt(0)" ::: "memory");                      \
    SB;                                                                     \
    MFMA_P(0, 0)                                                            \
    SB;                                                                     \
    /* P2 */                                                                \
    READ_B32(pbB, 1)                                                        \
    if ((STG) >= 1) STAGE_H(A, (U) + 1, 1);                                 \
    SB; BAR;                                                                \
    asm volatile("s_waitcnt lgkmcnt(0)" ::: "memory");                      \
    SB;                                                                     \
    MFMA_P(0, 1)                                                            \
    SB;                                                                     \
    /* P3 */                                                                \
    READ_A32(paA, 1)                                                        \
    if ((STG) >= 2) STAGE_H(B, (U) + 2, 0);                                 \
    SB; BAR;                                                                \
    asm volatile("s_waitcnt lgkmcnt(0)" ::: "memory");                      \
    SB;                                                                     \
    MFMA_P(1, 1)                                                            \
    SB;                                                                     \
    /* P4 */                                                                \
    if ((STG) >= 2) STAGE_H(B, (U) + 2, 1);                                 \
    SB;                                                                     \
    MFMA_P(1, 0)                                                            \
    asm volatile("s_waitcnt vmcnt(" VMSTR ")" ::: "memory");                \
    SB; BAR; SB;                                                            \
  }

__global__ __launch_bounds__(512, 2)
void gemm_bt256(const unsigned short* __restrict__ A,   // bf16 [M][K]
                const unsigned short* __restrict__ B,   // bf16 [N][K]
                const float* __restrict__ bias,
                float* __restrict__ out, int M)
{
    __shared__ __align__(16) unsigned short ldsA[2 * 2 * 8192];   // 64 KB
    __shared__ __align__(16) unsigned short ldsB[2 * 2 * 8192];   // 64 KB
    const char* ldsAc = (const char*)ldsA;
    const char* ldsBc = (const char*)ldsB;

    // XCD-aware bijective swizzle (nwg = 16*(M/256), divisible by 8)
    const int nwg = gridDim.x;
    const int bid = blockIdx.x;
    int swzb = bid;
    if ((nwg & 7) == 0) {
        const int cpx = nwg >> 3;
        swzb = (bid & 7) * cpx + (bid >> 3);
    }
    const int ntn = NDIM / 256;                 // 16
    const int n0 = (swzb % ntn) * 256;
    const int m0 = (swzb / ntn) * 256;

    const int tid  = threadIdx.x;
    const int lane = tid & 63;
    const int wid  = tid >> 6;
    const int wr   = wid >> 2;                  // A half (0..1)
    const int wc   = wid & 3;                   // 0..3
    const int bh   = wc >> 1;                   // B half
    const int bhw  = (wc & 1) * 8192;           // 64-row offset within B half (bytes)
    const int r32  = lane & 31;                 // row within 32-tile
    const int hi   = lane >> 5;                 // k sub-group (0..1)

    // frag read offset: row*128B + swizzled 16B slot ((ks*2 + hi) ^ (row&7));
    // ks*2+hi == (ks*2)^hi since hi<2, so addr = roff32 ^ (ks<<5).
    const int roff32 = r32 * 128 + (((hi ^ (r32 & 7)) & 7) << 4);

    // staging: linear LDS dest (tid*16B), inverse-swizzled global k source
    const int srow = tid >> 3;                  // 0..63
    const int sslot = (tid & 7) ^ (srow & 7);
    const unsigned short* srcA = A + (size_t)(m0 + srow) * KDIM + 8 * sslot;
    const unsigned short* srcB = B + (size_t)(n0 + srow) * KDIM + 8 * sslot;

    f32x16 acc32[4][2];
#pragma unroll
    for (int m = 0; m < 4; ++m)
#pragma unroll
        for (int n = 0; n < 2; ++n)
            acc32[m][n] = (f32x16)(0.0f);

    bf16x8 a_[2][4], b_[2][4];

    // ---- prologue: tile0 (A0,A1,B0,B1) + tile1 (B0,B1) = 12 gloads ----
    STAGE_H(A, 0, 0);
    STAGE_H(A, 0, 1);
    STAGE_H(B, 0, 0);
    STAGE_H(B, 0, 1);
    STAGE_H(B, 1, 0);
    STAGE_H(B, 1, 1);
    asm volatile("s_waitcnt vmcnt(4)" ::: "memory");   // tile 0 landed; B(1) in flight
    SB; BAR; SB;

    // ---- main: groups 0..61 ----
    for (int u = 0; u < 62; u += 2) {
        GROUP(u,     0, 2, "4");
        GROUP(u + 1, 1, 2, "4");
    }
    // ---- tail ----
    GROUP(62, 0, 1, "0");   // stages A(63) only; gate drains everything
    GROUP(63, 1, 0, "0");   // compute-only

    // ---- epilogue: C/D 32x32 layout ----
#pragma unroll
    for (int nf = 0; nf < 2; ++nf) {
        const int col = n0 + wc * 64 + nf * 32 + r32;
        const float bv = bias[col];
#pragma unroll
        for (int mf = 0; mf < 4; ++mf) {
            const size_t rb = (size_t)(m0 + wr * 128 + mf * 32 + hi * 4);
#pragma unroll
            for (int reg = 0; reg < 16; ++reg) {
                const size_t row = rb + (reg & 3) + 8 * (reg >> 2);
                out[row * NDIM + col] = acc32[mf][nf][reg] + bv;
            }
        }
    }
}

// ---------------- fallback (fused) for small ws ----------------
__global__ __launch_bounds__(256, 2)
void ssl_gemm_fused(const float* __restrict__ x, const float* __restrict__ w,
                    const float* __restrict__ bias, const int* __restrict__ rn,
                    float* __restrict__ out)
{
    __shared__ __align__(16) unsigned short As[128][40];
    __shared__ __align__(16) unsigned short Bs[128][40];

    const int R0 = rn[0], R1 = rn[1], R2 = rn[2], R3 = rn[3];
    const int tid = threadIdx.x;
    const int n0 = blockIdx.x * 128;
    const int m0 = blockIdx.y * 128;
    const int srow = tid >> 3;
    const int scol = (tid & 7) * 4;
    const int lane = tid & 63;
    const int wid  = tid >> 6;
    const int wr   = wid >> 1;
    const int wc   = wid & 1;
    const int lrow = lane & 15;
    const int lk   = (lane >> 4) * 8;

    f32x4 acc[4][4];
#pragma unroll
    for (int m = 0; m < 4; ++m)
#pragma unroll
        for (int n = 0; n < 4; ++n)
            acc[m][n] = (f32x4)(0.0f);

    for (int i = 0; i < KDIM / 32; ++i) {
        const int it   = i >> 1;
        const int k0   = i * 32;
#pragma unroll
        for (int p = 0; p < 4; ++p) {
            const int row = p * 32 + srow;
            const float4 v = *(const float4*)(x + (size_t)(m0 + row) * KDIM + k0 + scol);
            ushort4 s;
            s.x = f2bf(v.x); s.y = f2bf(v.y); s.z = f2bf(v.z); s.w = f2bf(v.w);
            *(ushort4*)&As[row][scol] = s;
        }
        const int hbase = R3 + R1 * (it + 1) + R0 * ((i & 1) + 1);
#pragma unroll
        for (int p = 0; p < 4; ++p) {
            const int nl = p * 32 + srow;
            const int j  = (n0 + nl) >> 5;
            const int off = 32 - (((hbase + R2 * j) << 2) & 31);
            const float4 v = *(const float4*)(w + (size_t)(n0 + nl) * REDIN + it * 32 + scol);
            Bs[nl][(scol + 0 - off) & 31] = f2bf(v.x);
            Bs[nl][(scol + 1 - off) & 31] = f2bf(v.y);
            Bs[nl][(scol + 2 - off) & 31] = f2bf(v.z);
            Bs[nl][(scol + 3 - off) & 31] = f2bf(v.w);
        }
        __syncthreads();

        bf16x8 af[4], bfr[4];
#pragma unroll
        for (int m = 0; m < 4; ++m)
            af[m] = *(const bf16x8*)&As[wr * 64 + m * 16 + lrow][lk];
#pragma unroll
        for (int n = 0; n < 4; ++n)
            bfr[n] = *(const bf16x8*)&Bs[wc * 64 + n * 16 + lrow][lk];
#pragma unroll
        for (int m = 0; m < 4; ++m)
#pragma unroll
            for (int n = 0; n < 4; ++n)
                acc[m][n] = __builtin_amdgcn_mfma_f32_16x16x32_bf16(af[m], bfr[n], acc[m][n], 0, 0, 0);
        __syncthreads();
    }

#pragma unroll
    for (int n = 0; n < 4; ++n) {
        const int col = n0 + wc * 64 + n * 16 + lrow;
        const float bv = bias[col];
#pragma unroll
        for (int m = 0; m < 4; ++m) {
            const int rbase = m0 + wr * 64 + m * 16 + (lane >> 4) * 4;
#pragma unroll
            for (int e = 0; e < 4; ++e)
                out[(size_t)(rbase + e) * NDIM + col] = acc[m][n][e] + bv;
        }
    }
}

extern "C" void kernel_launch(void* const* d_in, const int* in_sizes, int n_in,
                              void* d_out, int out_size, void* d_ws, size_t ws_size,
                              hipStream_t stream) {
    const float* x    = (const float*)d_in[0];
    const float* wgt  = (const float*)d_in[1];
    const float* bias = (const float*)d_in[2];
    const int*   rn   = (const int*)d_in[3];
    float* out = (float*)d_out;

    const int M = in_sizes[0] / KDIM;                       // 8192
    const size_t need = ((size_t)M * KDIM + (size_t)NDIM * KDIM) * sizeof(unsigned short);

    if (ws_size >= need && (M % 256) == 0) {
        unsigned short* xb = (unsigned short*)d_ws;
        unsigned short* wx = xb + (size_t)M * KDIM;

        cvt_x<<<2048, 256, 0, stream>>>(x, xb, (long)M * KDIM / 8);
        expand_w<<<2048, 256, 0, stream>>>(wgt, wx, rn);

        const int nwg = (NDIM / 256) * (M / 256);           // 512
        gemm_bt256<<<nwg, 512, 0, stream>>>(xb, wx, bias, out, M);
    } else {
        dim3 grid(NDIM / 128, M / 128);
        ssl_gemm_fused<<<grid, dim3(256), 0, stream>>>(x, wgt, bias, rn, out);
    }
}

// Round 11
// 272.755 us; speedup vs baseline: 1.1035x; 1.1035x over previous
//
#include <hip/hip_runtime.h>

typedef __bf16 bf16x8 __attribute__((ext_vector_type(8)));
typedef float  f32x4  __attribute__((ext_vector_type(4)));
typedef unsigned short ushort8 __attribute__((ext_vector_type(8)));

#define KDIM  4096
#define NDIM  4096
#define REDIN 2048

static __device__ __forceinline__ unsigned short f2bf(float f) {
    return __builtin_bit_cast(unsigned short, (__bf16)f);
}

typedef __attribute__((address_space(3))) void       lds_void;
typedef const __attribute__((address_space(1))) void gbl_cvoid;

static __device__ __forceinline__ void gload16(const void* g, void* l) {
    __builtin_amdgcn_global_load_lds((gbl_cvoid*)g, (lds_void*)l, 16, 0, 0);
}

// ---------------- fused prep: blocks [0,2048) convert x; [2048,3072) expand w ----------------
__global__ void prep_fused(const float* __restrict__ x, const float* __restrict__ w,
                           const int* __restrict__ rn,
                           unsigned short* __restrict__ xb, unsigned short* __restrict__ wx,
                           long n8x) {
    if (blockIdx.x < 2048) {
        long idx = (long)blockIdx.x * blockDim.x + threadIdx.x;
        long stride = (long)2048 * blockDim.x;
        for (long i = idx; i < n8x; i += stride) {
            const float4 a = ((const float4*)x)[2 * i];
            const float4 b = ((const float4*)x)[2 * i + 1];
            ushort8 s;
            s[0] = f2bf(a.x); s[1] = f2bf(a.y); s[2] = f2bf(a.z); s[3] = f2bf(a.w);
            s[4] = f2bf(b.x); s[5] = f2bf(b.y); s[6] = f2bf(b.z); s[7] = f2bf(b.w);
            ((ushort8*)xb)[i] = s;
        }
    } else {
        const int R0 = rn[0], R1 = rn[1], R2 = rn[2], R3 = rn[3];
        const long total = (long)NDIM * (KDIM / 8);
        long idx = (long)(blockIdx.x - 2048) * blockDim.x + threadIdx.x;
        long stride = (long)1024 * blockDim.x;
        for (long t = idx; t < total; t += stride) {
            const int kp = (int)(t & (KDIM / 8 - 1));
            const int n  = (int)(t >> 9);
            const int k0 = kp * 8;
            const int i  = k0 >> 5;
            const int kk0 = k0 & 31;
            const int it = i >> 1;
            const int h  = R3 + R2 * (n >> 5) + R1 * (it + 1) + R0 * ((i & 1) + 1);
            const int off = 32 - ((h << 2) & 31);
            const float* src = w + (long)n * REDIN + it * 32;
            ushort8 s;
#pragma unroll
            for (int q = 0; q < 8; ++q)
                s[q] = f2bf(src[(kk0 + q + off) & 31]);
            ((ushort8*)wx)[t] = s;
        }
    }
}

// ======== main GEMM: 256x256, BK=64, 2-buf ring, 4 phases/group, 1 bar/phase (R7 + early A-h1) ========
// 8 waves 2Mx4N, per-wave 128x64. LDS: A[2buf][2half][128][64]bf16 64KB + B same.
// Bank swizzle (R7-proven, 0 conflicts): phys 16B slot = logical ^ (row&7);
// linear gload dest + inverse-swizzled global source + swizzled ds_read.
// Group u (tile u from buf u&1), 4 phases, ONE barrier per phase:
//   P1: read A(mh0)x8 + B(nh0)x4; stage A(u+1) h0+h1; lgkm(4); BAR; lgkm(0); MFMA(0,0)
//   P2: read B(nh1)x4;                                      BAR; lgkm(0); MFMA(0,1)
//   P3: read A(mh1)x8;            stage B(u+2)h0;           BAR; lgkm(0); MFMA(1,1)
//   P4: stage B(u+2)h1; MFMA(1,0); vmcnt(4); BAR
// Only delta vs R7 (passed, 246us): A(u+1)h1 staged at P1 instead of P2 -> its
// prefetch distance to the P4 vmcnt gate grows from ~2 to ~3 phases (> HBM latency).
// WAR audit for A(u+1) stage @P1(u): overwrites A-buf[(u+1)&1]; last reads of that
// buffer were P3(u-1) (drained at lgkm(0) before MFMA(1,1) < BAR(P4,u-1) < P1(u) stage). OK.
// B stages and the vmcnt(4) gate: identical to R7's audited graph. All frag reads occur
// only after a barrier that every wave reaches having vmcnt-drained its tile-(u) loads. OK.

#define STAGE_H(MAT, T, HALF)                                               \
  {                                                                         \
    char* _d = (char*)lds##MAT + ((((T) & 1) * 2 + (HALF)) * 16384) + tid * 16; \
    const unsigned short* _s = src##MAT + (size_t)((HALF) * 128) * KDIM + (size_t)(T) * 64; \
    gload16(_s, _d);                                                        \
    gload16(_s + (size_t)64 * KDIM, _d + 8192);                             \
  }

#define READ_A(PA, MH)                                                      \
  _Pragma("unroll")                                                         \
  for (int _kk = 0; _kk < 2; ++_kk)                                         \
    _Pragma("unroll")                                                       \
    for (int _mf = 0; _mf < 4; ++_mf)                                       \
      a_[_kk][_mf] = *(const bf16x8*)((PA) + (MH) * 8192 + _mf * 2048 + (roff ^ (_kk << 6)));

#define READ_B(PB, NH)                                                      \
  _Pragma("unroll")                                                         \
  for (int _kk = 0; _kk < 2; ++_kk)                                         \
    _Pragma("unroll")                                                       \
    for (int _nf = 0; _nf < 2; ++_nf)                                       \
      b_##NH[_kk][_nf] = *(const bf16x8*)((PB) + (NH) * 4096 + _nf * 2048 + (roff ^ (_kk << 6)));

#define MFMA_Q(MH, NH)                                                      \
  __builtin_amdgcn_s_setprio(1);                                            \
  _Pragma("unroll")                                                         \
  for (int _kk = 0; _kk < 2; ++_kk)                                         \
    _Pragma("unroll")                                                       \
    for (int _mf = 0; _mf < 4; ++_mf)                                       \
      _Pragma("unroll")                                                     \
      for (int _nf = 0; _nf < 2; ++_nf)                                     \
        acc[(MH) * 4 + _mf][(NH) * 2 + _nf] = __builtin_amdgcn_mfma_f32_16x16x32_bf16( \
            a_[_kk][_mf], b_##NH[_kk][_nf], acc[(MH) * 4 + _mf][(NH) * 2 + _nf], 0, 0, 0); \
  __builtin_amdgcn_s_setprio(0);

#define SB __builtin_amdgcn_sched_barrier(0)
#define BAR __builtin_amdgcn_s_barrier()

#define GROUP(U, BUF, STG, VMSTR)                                           \
  {                                                                         \
    const char* paA = ldsAc + ((BUF) * 2 + wr) * 16384;                     \
    const char* pbB = ldsBc + ((BUF) * 2 + bh) * 16384 + bhw;               \
    /* P1 */                                                                \
    READ_A(paA, 0)                                                          \
    READ_B(pbB, 0)                                                          \
    if ((STG) >= 1) { STAGE_H(A, (U) + 1, 0); STAGE_H(A, (U) + 1, 1); }     \
    asm volatile("s_waitcnt lgkmcnt(4)" ::: "memory");                      \
    SB; BAR;                                                                \
    asm volatile("s_waitcnt lgkmcnt(0)" ::: "memory");                      \
    SB;                                                                     \
    MFMA_Q(0, 0)                                                            \
    SB;                                                                     \
    /* P2 */                                                                \
    READ_B(pbB, 1)                                                          \
    SB; BAR;                                                                \
    asm volatile("s_waitcnt lgkmcnt(0)" ::: "memory");                      \
    SB;                                                                     \
    MFMA_Q(0, 1)                                                            \
    SB;                                                                     \
    /* P3 */                                                                \
    READ_A(paA, 1)                                                          \
    if ((STG) >= 2) STAGE_H(B, (U) + 2, 0);                                 \
    SB; BAR;                                                                \
    asm volatile("s_waitcnt lgkmcnt(0)" ::: "memory");                      \
    SB;                                                                     \
    MFMA_Q(1, 1)                                                            \
    SB;                                                                     \
    /* P4 */                                                                \
    if ((STG) >= 2) STAGE_H(B, (U) + 2, 1);                                 \
    SB;                                                                     \
    MFMA_Q(1, 0)                                                            \
    asm volatile("s_waitcnt vmcnt(" VMSTR ")" ::: "memory");                \
    SB; BAR; SB;                                                            \
  }

__global__ __launch_bounds__(512, 2)
void gemm_bt256(const unsigned short* __restrict__ A,   // bf16 [M][K]
                const unsigned short* __restrict__ B,   // bf16 [N][K]
                const float* __restrict__ bias,
                float* __restrict__ out, int M)
{
    __shared__ __align__(16) unsigned short ldsA[2 * 2 * 8192];   // 64 KB
    __shared__ __align__(16) unsigned short ldsB[2 * 2 * 8192];   // 64 KB
    const char* ldsAc = (const char*)ldsA;
    const char* ldsBc = (const char*)ldsB;

    // XCD-aware bijective swizzle (nwg = 16*(M/256), divisible by 8)
    const int nwg = gridDim.x;
    const int bid = blockIdx.x;
    int swzb = bid;
    if ((nwg & 7) == 0) {
        const int cpx = nwg >> 3;
        swzb = (bid & 7) * cpx + (bid >> 3);
    }
    const int ntn = NDIM / 256;                 // 16
    const int n0 = (swzb % ntn) * 256;
    const int m0 = (swzb / ntn) * 256;

    const int tid  = threadIdx.x;
    const int lane = tid & 63;
    const int wid  = tid >> 6;
    const int wr   = wid >> 2;                  // A half (0..1)
    const int wc   = wid & 3;                   // 0..3
    const int bh   = wc >> 1;                   // B half
    const int bhw  = (wc & 1) * 8192;           // 64-row offset within B half (bytes)
    const int lrow = lane & 15;
    const int g    = lane >> 4;                 // k sub-group 0..3

    // frag read offset: row*128B + swizzled 16B slot
    const int roff = lrow * 128 + (((g ^ (lrow & 7)) & 7) << 4);

    // staging: linear LDS dest (tid*16B), inverse-swizzled global k source
    const int srow = tid >> 3;                  // 0..63
    const int sslot = (tid & 7) ^ (srow & 7);
    const unsigned short* srcA = A + (size_t)(m0 + srow) * KDIM + 8 * sslot;
    const unsigned short* srcB = B + (size_t)(n0 + srow) * KDIM + 8 * sslot;

    f32x4 acc[8][4];
#pragma unroll
    for (int m = 0; m < 8; ++m)
#pragma unroll
        for (int n = 0; n < 4; ++n)
            acc[m][n] = (f32x4)(0.0f);

    bf16x8 a_[2][4], b_0[2][2], b_1[2][2];

    // ---- prologue: tile0 (A0,A1,B0,B1) + tile1 (B0,B1) = 12 gloads ----
    STAGE_H(A, 0, 0);
    STAGE_H(A, 0, 1);
    STAGE_H(B, 0, 0);
    STAGE_H(B, 0, 1);
    STAGE_H(B, 1, 0);
    STAGE_H(B, 1, 1);
    asm volatile("s_waitcnt vmcnt(4)" ::: "memory");   // tile 0 landed; B(1) in flight
    SB; BAR; SB;

    // ---- main: groups 0..61 ----
    for (int u = 0; u < 62; u += 2) {
        GROUP(u,     0, 2, "4");
        GROUP(u + 1, 1, 2, "4");
    }
    // ---- tail ----
    GROUP(62, 0, 1, "0");   // stages A(63) only; gate drains everything
    GROUP(63, 1, 0, "0");   // compute-only

    // ---- epilogue ----
#pragma unroll
    for (int n = 0; n < 4; ++n) {
        const int col = n0 + wc * 64 + n * 16 + lrow;
        const float bv = bias[col];
#pragma unroll
        for (int m = 0; m < 8; ++m) {
            const size_t rbase = (size_t)(m0 + wr * 128 + m * 16 + (lane >> 4) * 4);
#pragma unroll
            for (int e = 0; e < 4; ++e)
                out[(rbase + e) * NDIM + col] = acc[m][n][e] + bv;
        }
    }
}

// ---------------- fallback (fused) for small ws ----------------
__global__ __launch_bounds__(256, 2)
void ssl_gemm_fused(const float* __restrict__ x, const float* __restrict__ w,
                    const float* __restrict__ bias, const int* __restrict__ rn,
                    float* __restrict__ out)
{
    __shared__ __align__(16) unsigned short As[128][40];
    __shared__ __align__(16) unsigned short Bs[128][40];

    const int R0 = rn[0], R1 = rn[1], R2 = rn[2], R3 = rn[3];
    const int tid = threadIdx.x;
    const int n0 = blockIdx.x * 128;
    const int m0 = blockIdx.y * 128;
    const int srow = tid >> 3;
    const int scol = (tid & 7) * 4;
    const int lane = tid & 63;
    const int wid  = tid >> 6;
    const int wr   = wid >> 1;
    const int wc   = wid & 1;
    const int lrow = lane & 15;
    const int lk   = (lane >> 4) * 8;

    f32x4 acc[4][4];
#pragma unroll
    for (int m = 0; m < 4; ++m)
#pragma unroll
        for (int n = 0; n < 4; ++n)
            acc[m][n] = (f32x4)(0.0f);

    for (int i = 0; i < KDIM / 32; ++i) {
        const int it   = i >> 1;
        const int k0   = i * 32;
#pragma unroll
        for (int p = 0; p < 4; ++p) {
            const int row = p * 32 + srow;
            const float4 v = *(const float4*)(x + (size_t)(m0 + row) * KDIM + k0 + scol);
            ushort4 s;
            s.x = f2bf(v.x); s.y = f2bf(v.y); s.z = f2bf(v.z); s.w = f2bf(v.w);
            *(ushort4*)&As[row][scol] = s;
        }
        const int hbase = R3 + R1 * (it + 1) + R0 * ((i & 1) + 1);
#pragma unroll
        for (int p = 0; p < 4; ++p) {
            const int nl = p * 32 + srow;
            const int j  = (n0 + nl) >> 5;
            const int off = 32 - (((hbase + R2 * j) << 2) & 31);
            const float4 v = *(const float4*)(w + (size_t)(n0 + nl) * REDIN + it * 32 + scol);
            Bs[nl][(scol + 0 - off) & 31] = f2bf(v.x);
            Bs[nl][(scol + 1 - off) & 31] = f2bf(v.y);
            Bs[nl][(scol + 2 - off) & 31] = f2bf(v.z);
            Bs[nl][(scol + 3 - off) & 31] = f2bf(v.w);
        }
        __syncthreads();

        bf16x8 af[4], bfr[4];
#pragma unroll
        for (int m = 0; m < 4; ++m)
            af[m] = *(const bf16x8*)&As[wr * 64 + m * 16 + lrow][lk];
#pragma unroll
        for (int n = 0; n < 4; ++n)
            bfr[n] = *(const bf16x8*)&Bs[wc * 64 + n * 16 + lrow][lk];
#pragma unroll
        for (int m = 0; m < 4; ++m)
#pragma unroll
            for (int n = 0; n < 4; ++n)
                acc[m][n] = __builtin_amdgcn_mfma_f32_16x16x32_bf16(af[m], bfr[n], acc[m][n], 0, 0, 0);
        __syncthreads();
    }

#pragma unroll
    for (int n = 0; n < 4; ++n) {
        const int col = n0 + wc * 64 + n * 16 + lrow;
        const float bv = bias[col];
#pragma unroll
        for (int m = 0; m < 4; ++m) {
            const int rbase = m0 + wr * 64 + m * 16 + (lane >> 4) * 4;
#pragma unroll
            for (int e = 0; e < 4; ++e)
                out[(size_t)(rbase + e) * NDIM + col] = acc[m][n][e] + bv;
        }
    }
}

extern "C" void kernel_launch(void* const* d_in, const int* in_sizes, int n_in,
                              void* d_out, int out_size, void* d_ws, size_t ws_size,
                              hipStream_t stream) {
    const float* x    = (const float*)d_in[0];
    const float* wgt  = (const float*)d_in[1];
    const float* bias = (const float*)d_in[2];
    const int*   rn   = (const int*)d_in[3];
    float* out = (float*)d_out;

    const int M = in_sizes[0] / KDIM;                       // 8192
    const size_t need = ((size_t)M * KDIM + (size_t)NDIM * KDIM) * sizeof(unsigned short);

    if (ws_size >= need && (M % 256) == 0) {
        unsigned short* xb = (unsigned short*)d_ws;
        unsigned short* wx = xb + (size_t)M * KDIM;

        prep_fused<<<3072, 256, 0, stream>>>(x, wgt, rn, xb, wx, (long)M * KDIM / 8);

        const int nwg = (NDIM / 256) * (M / 256);           // 512
        gemm_bt256<<<nwg, 512, 0, stream>>>(xb, wx, bias, out, M);
    } else {
        dim3 grid(NDIM / 128, M / 128);
        ssl_gemm_fused<<<grid, dim3(256), 0, stream>>>(x, wgt, bias, rn, out);
    }
}